// Round 3
// baseline (428.531 us; speedup 1.0000x reference)
//
#include <hip/hip_runtime.h>

#define IN_CH 128
#define HID 64
#define NEG 0.2f

// ---------------- K1: projections xl = x@W_l.T, xr = x@W_r.T ----------------
// Tiled GEMM: 64 nodes x 64 ch per block, 4x4 register tile per thread.
// x4s: [c4][node] float4, skewed stride 65 -> compute reads 2-way (free).
// Wsh: [k][c] transposed, stride 65 -> compute reads conflict-free broadcast.
__global__ __launch_bounds__(256) void proj_kernel(
    const float* __restrict__ x, const float* __restrict__ W_l,
    const float* __restrict__ W_r,
    float* __restrict__ xl, float* __restrict__ xr, int nN)
{
    __shared__ float4 x4s[32 * 65];     // 33.3 KB
    __shared__ float  Wsh[128 * 65];    // 33.3 KB
    int tid = threadIdx.x;
    int nb = blockIdx.x * 64;

    // stage x tile: 64 nodes x 32 float4
    #pragma unroll
    for (int i = 0; i < 8; ++i) {
        int gi = i * 256 + tid;
        int nl = gi >> 5, c4 = gi & 31;
        int node = nb + nl;
        if (node < nN)
            x4s[c4 * 65 + nl] = *(const float4*)(x + (size_t)node * IN_CH + c4 * 4);
    }

    int tn = tid & 15, tc = tid >> 4;   // node group / channel group

    for (int m = 0; m < 2; ++m) {
        const float* __restrict__ W = m ? W_r : W_l;
        float* __restrict__ dstv = m ? xr : xl;
        __syncthreads();   // Wsh safe to overwrite (prev phase readers done)
        #pragma unroll
        for (int i = 0; i < 8; ++i) {
            int gi = i * 256 + tid;
            int c = gi >> 5, k4 = gi & 31;
            float4 wv = *(const float4*)(W + c * IN_CH + k4 * 4);
            Wsh[(4 * k4 + 0) * 65 + c] = wv.x;
            Wsh[(4 * k4 + 1) * 65 + c] = wv.y;
            Wsh[(4 * k4 + 2) * 65 + c] = wv.z;
            Wsh[(4 * k4 + 3) * 65 + c] = wv.w;
        }
        __syncthreads();

        float acc[4][4];
        #pragma unroll
        for (int i = 0; i < 4; ++i)
            #pragma unroll
            for (int j = 0; j < 4; ++j) acc[i][j] = 0.f;

        #pragma unroll 2
        for (int c4 = 0; c4 < 32; ++c4) {
            float4 xv0 = x4s[c4 * 65 + tn];
            float4 xv1 = x4s[c4 * 65 + tn + 16];
            float4 xv2 = x4s[c4 * 65 + tn + 32];
            float4 xv3 = x4s[c4 * 65 + tn + 48];
            const float* wrow = Wsh + (c4 * 4) * 65 + tc * 4;
            float4 w0 = *(const float4*)(wrow);
            float4 w1 = *(const float4*)(wrow + 65);
            float4 w2 = *(const float4*)(wrow + 130);
            float4 w3 = *(const float4*)(wrow + 195);
            #pragma unroll
            for (int j = 0; j < 4; ++j) {
                float wa = (&w0.x)[j], wb = (&w1.x)[j], wc = (&w2.x)[j], wd = (&w3.x)[j];
                acc[0][j] = fmaf(xv0.x, wa, acc[0][j]);
                acc[0][j] = fmaf(xv0.y, wb, acc[0][j]);
                acc[0][j] = fmaf(xv0.z, wc, acc[0][j]);
                acc[0][j] = fmaf(xv0.w, wd, acc[0][j]);
                acc[1][j] = fmaf(xv1.x, wa, acc[1][j]);
                acc[1][j] = fmaf(xv1.y, wb, acc[1][j]);
                acc[1][j] = fmaf(xv1.z, wc, acc[1][j]);
                acc[1][j] = fmaf(xv1.w, wd, acc[1][j]);
                acc[2][j] = fmaf(xv2.x, wa, acc[2][j]);
                acc[2][j] = fmaf(xv2.y, wb, acc[2][j]);
                acc[2][j] = fmaf(xv2.z, wc, acc[2][j]);
                acc[2][j] = fmaf(xv2.w, wd, acc[2][j]);
                acc[3][j] = fmaf(xv3.x, wa, acc[3][j]);
                acc[3][j] = fmaf(xv3.y, wb, acc[3][j]);
                acc[3][j] = fmaf(xv3.z, wc, acc[3][j]);
                acc[3][j] = fmaf(xv3.w, wd, acc[3][j]);
            }
        }
        #pragma unroll
        for (int i = 0; i < 4; ++i) {
            int node = nb + tn + 16 * i;
            if (node < nN) {
                float4 o = make_float4(acc[i][0], acc[i][1], acc[i][2], acc[i][3]);
                *(float4*)(dstv + (size_t)node * HID + tc * 4) = o;
            }
        }
    }
}

// ---------------- K2: in-degree histogram (4 edges/thread) ----------------
__global__ __launch_bounds__(256) void hist_kernel(
    const int* __restrict__ dst, int* __restrict__ deg, int E)
{
    int i = (blockIdx.x * 256 + threadIdx.x) * 4;
    if (i + 3 < E) {
        int4 v = *(const int4*)(dst + i);
        atomicAdd(&deg[v.x], 1);
        atomicAdd(&deg[v.y], 1);
        atomicAdd(&deg[v.z], 1);
        atomicAdd(&deg[v.w], 1);
    } else {
        for (; i < E; ++i) atomicAdd(&deg[dst[i]], 1);
    }
}

// ---------------- K3: exclusive scan (single block, int4 chunks of 4096) ----
__global__ __launch_bounds__(1024) void scan_kernel(
    const int* __restrict__ deg, int* __restrict__ row_start,
    int* __restrict__ cursor, int np)
{
    __shared__ int wsum[16];
    __shared__ int running_s;
    int tid = threadIdx.x, lane = tid & 63, w = tid >> 6;
    if (tid == 0) running_s = 0;
    __syncthreads();
    for (int base = 0; base < np; base += 4096) {
        int i = base + tid * 4;
        int4 v = *(const int4*)(deg + i);
        int p0 = v.x, p1 = p0 + v.y, p2 = p1 + v.z, p3 = p2 + v.w;
        int sv = p3;
        #pragma unroll
        for (int d = 1; d < 64; d <<= 1) {
            int t = __shfl_up(sv, d, 64);
            if (lane >= d) sv += t;
        }
        if (lane == 63) wsum[w] = sv;
        __syncthreads();
        if (tid < 16) {
            int t = wsum[tid];
            #pragma unroll
            for (int d = 1; d < 16; d <<= 1) {
                int u = __shfl_up(t, d, 64);
                if (tid >= d) t += u;
            }
            wsum[tid] = t;
        }
        __syncthreads();
        int run0 = running_s;
        int excl = run0 + (w ? wsum[w - 1] : 0) + sv - p3;  // thread-exclusive
        int4 o = make_int4(excl, excl + p0, excl + p1, excl + p2);
        *(int4*)(row_start + i) = o;
        *(int4*)(cursor + i) = o;
        __syncthreads();
        if (tid == 0) running_s = run0 + wsum[15];
        __syncthreads();
    }
}

// ---------------- K4: scatter edges into CSR slots (4 edges/thread) --------
__global__ __launch_bounds__(256) void scatter_kernel(
    const int* __restrict__ src, const int* __restrict__ dst,
    int* __restrict__ cursor, int* __restrict__ csr, int E)
{
    int i = (blockIdx.x * 256 + threadIdx.x) * 4;
    if (i + 3 < E) {
        int4 sv = *(const int4*)(src + i);
        int4 dv = *(const int4*)(dst + i);
        int p0 = atomicAdd(&cursor[dv.x], 1); csr[p0] = sv.x;
        int p1 = atomicAdd(&cursor[dv.y], 1); csr[p1] = sv.y;
        int p2 = atomicAdd(&cursor[dv.z], 1); csr[p2] = sv.z;
        int p3 = atomicAdd(&cursor[dv.w], 1); csr[p3] = sv.w;
    } else {
        for (; i < E; ++i) {
            int p = atomicAdd(&cursor[dst[i]], 1);
            csr[p] = src[i];
        }
    }
}

// ---------------- K5: fused attention + aggregation + ELU + linear ----------
// One wave per node; wave splits into 4 groups x 16 lanes; lane = 4 channels.
__global__ __launch_bounds__(256) void gat_main(
    const float* __restrict__ xl, const float* __restrict__ xr,
    const int* __restrict__ row_start, const int* __restrict__ row_end,
    const int* __restrict__ csr,
    const float* __restrict__ att, const float* __restrict__ bias_conv,
    const float* __restrict__ W_lin, const float* __restrict__ b_lin,
    float* __restrict__ out, int nN)
{
    __shared__ float WT[64 * 65];   // WT[c*65+o] = W_lin[o][c], +1 pad
    __shared__ float hbuf[4][64];
    int tid = threadIdx.x;
    for (int idx = tid; idx < 64 * 64; idx += 256) {
        int o = idx >> 6, c = idx & 63;
        WT[c * 65 + o] = W_lin[idx];
    }
    int lane = tid & 63, w = tid >> 6;
    int g = lane >> 4, gl = lane & 15;
    int node = blockIdx.x * 4 + w;
    bool active = node < nN;
    if (active) {
        const float4 att4 = *(const float4*)(att + gl * 4);
        const float4 xr4  = *(const float4*)(xr + (size_t)node * HID + gl * 4);
        float4 acc = make_float4(0.f, 0.f, 0.f, 0.f);
        float denom = 0.f;
        // self loop: group 0 only
        if (g == 0) {
            float4 xs = *(const float4*)(xl + (size_t)node * HID + gl * 4);
            float tx = xs.x + xr4.x, ty = xs.y + xr4.y;
            float tz = xs.z + xr4.z, tw = xs.w + xr4.w;
            float lx = fmaxf(tx, 0.f) + NEG * fminf(tx, 0.f);
            float ly = fmaxf(ty, 0.f) + NEG * fminf(ty, 0.f);
            float lz = fmaxf(tz, 0.f) + NEG * fminf(tz, 0.f);
            float lw = fmaxf(tw, 0.f) + NEG * fminf(tw, 0.f);
            float r = att4.x * lx;
            r = fmaf(att4.y, ly, r); r = fmaf(att4.z, lz, r); r = fmaf(att4.w, lw, r);
            r += __shfl_xor(r, 1, 64);
            r += __shfl_xor(r, 2, 64);
            r += __shfl_xor(r, 4, 64);
            r += __shfl_xor(r, 8, 64);
            float ev = __expf(r);
            denom = ev;
            acc.x = ev * xs.x; acc.y = ev * xs.y;
            acc.z = ev * xs.z; acc.w = ev * xs.w;
        }
        int s = row_start[node], e = row_end[node];
        for (int base = s; base < e; base += 4) {
            int k = base + g;
            int kc = (k < e) ? k : (e - 1);
            int j = csr[kc];
            float4 xj = *(const float4*)(xl + (size_t)j * HID + gl * 4);
            float tx = xj.x + xr4.x, ty = xj.y + xr4.y;
            float tz = xj.z + xr4.z, tw = xj.w + xr4.w;
            float lx = fmaxf(tx, 0.f) + NEG * fminf(tx, 0.f);
            float ly = fmaxf(ty, 0.f) + NEG * fminf(ty, 0.f);
            float lz = fmaxf(tz, 0.f) + NEG * fminf(tz, 0.f);
            float lw = fmaxf(tw, 0.f) + NEG * fminf(tw, 0.f);
            float r = att4.x * lx;
            r = fmaf(att4.y, ly, r); r = fmaf(att4.z, lz, r); r = fmaf(att4.w, lw, r);
            r += __shfl_xor(r, 1, 64);
            r += __shfl_xor(r, 2, 64);
            r += __shfl_xor(r, 4, 64);
            r += __shfl_xor(r, 8, 64);
            float ev = __expf(r);
            if (k >= e) ev = 0.f;
            denom += ev;
            acc.x = fmaf(ev, xj.x, acc.x);
            acc.y = fmaf(ev, xj.y, acc.y);
            acc.z = fmaf(ev, xj.z, acc.z);
            acc.w = fmaf(ev, xj.w, acc.w);
        }
        // cross-group combine
        denom += __shfl_xor(denom, 16, 64);
        denom += __shfl_xor(denom, 32, 64);
        acc.x += __shfl_xor(acc.x, 16, 64); acc.x += __shfl_xor(acc.x, 32, 64);
        acc.y += __shfl_xor(acc.y, 16, 64); acc.y += __shfl_xor(acc.y, 32, 64);
        acc.z += __shfl_xor(acc.z, 16, 64); acc.z += __shfl_xor(acc.z, 32, 64);
        acc.w += __shfl_xor(acc.w, 16, 64); acc.w += __shfl_xor(acc.w, 32, 64);
        float inv = 1.f / (denom + 1e-16f);
        float4 b4 = *(const float4*)(bias_conv + gl * 4);
        float hx = fmaf(acc.x, inv, b4.x);
        float hy = fmaf(acc.y, inv, b4.y);
        float hz = fmaf(acc.z, inv, b4.z);
        float hw = fmaf(acc.w, inv, b4.w);
        hx = (hx > 0.f) ? hx : (__expf(hx) - 1.f);
        hy = (hy > 0.f) ? hy : (__expf(hy) - 1.f);
        hz = (hz > 0.f) ? hz : (__expf(hz) - 1.f);
        hw = (hw > 0.f) ? hw : (__expf(hw) - 1.f);
        if (g == 0) {
            *(float4*)(&hbuf[w][gl * 4]) = make_float4(hx, hy, hz, hw);
        }
    }
    __syncthreads();   // covers WT staging + hbuf writes
    if (active) {
        float y = b_lin[lane];
        #pragma unroll 8
        for (int c = 0; c < 64; ++c)
            y = fmaf(WT[c * 65 + lane], hbuf[w][c], y);
        out[(size_t)node * 64 + lane] = y;
    }
}

extern "C" void kernel_launch(void* const* d_in, const int* in_sizes, int n_in,
                              void* d_out, int out_size, void* d_ws, size_t ws_size,
                              hipStream_t stream) {
    const float* x      = (const float*)d_in[0];
    const int*   ei     = (const int*)d_in[1];
    // d_in[2] = edge_weight: unused by the reference
    const float* W_l    = (const float*)d_in[3];
    const float* W_r    = (const float*)d_in[4];
    const float* att    = (const float*)d_in[5];
    const float* bias_c = (const float*)d_in[6];
    const float* W_lin  = (const float*)d_in[7];
    const float* b_lin  = (const float*)d_in[8];
    float* out = (float*)d_out;

    int N = in_sizes[0] / IN_CH;
    int E = in_sizes[2];
    const int* srcp = ei;
    const int* dstp = ei + E;

    int NP = ((N + 4095) / 4096) * 4096;   // padded for int4 scan

    char* ws = (char*)d_ws;
    float* xl = (float*)ws;
    float* xr = xl + (size_t)N * HID;
    int* deg       = (int*)(xr + (size_t)N * HID);
    int* row_start = deg + NP;
    int* cursor    = row_start + NP;
    int* csr       = cursor + NP;

    hipMemsetAsync(deg, 0, (size_t)NP * sizeof(int), stream);
    proj_kernel<<<(N + 63) / 64, 256, 0, stream>>>(x, W_l, W_r, xl, xr, N);
    hist_kernel<<<(E / 4 + 255) / 256, 256, 0, stream>>>(dstp, deg, E);
    scan_kernel<<<1, 1024, 0, stream>>>(deg, row_start, cursor, NP);
    scatter_kernel<<<(E / 4 + 255) / 256, 256, 0, stream>>>(srcp, dstp, cursor, csr, E);
    gat_main<<<(N + 3) / 4, 256, 0, stream>>>(xl, xr, row_start, cursor, csr,
                                              att, bias_c, W_lin, b_lin, out, N);
}

// Round 4
// 383.233 us; speedup vs baseline: 1.1182x; 1.1182x over previous
//
#include <hip/hip_runtime.h>

#define IN_CH 128
#define HID 64
#define NEG 0.2f

// ---------------- K1: projections xl = x@W_l.T, xr = x@W_r.T ----------------
// LDS holds ONLY x, float-transposed xT[k][node] stride 66 (2-way reads, free).
// W is read via wave-uniform scalar loads (readfirstlane) -> SGPR broadcast.
// Thread = 1 node x 32 ch; wave w: matrix = w>>1, ch-half = (w&1)*32.
__global__ __launch_bounds__(256) void proj_kernel(
    const float* __restrict__ x, const float* __restrict__ W_l,
    const float* __restrict__ W_r,
    float* __restrict__ xl, float* __restrict__ xr, int nN)
{
    __shared__ float xT[128 * 66];   // 33.8 KB
    int tid = threadIdx.x;
    int nb = blockIdx.x * 64;

    // stage x tile transposed: 64 nodes x 128 ch
    #pragma unroll
    for (int i = 0; i < 8; ++i) {
        int gi = i * 256 + tid;
        int nl = gi >> 5, c4 = gi & 31;
        int node = nb + nl;
        if (node < nN) {
            float4 xv = *(const float4*)(x + (size_t)node * IN_CH + c4 * 4);
            xT[(4 * c4 + 0) * 66 + nl] = xv.x;
            xT[(4 * c4 + 1) * 66 + nl] = xv.y;
            xT[(4 * c4 + 2) * 66 + nl] = xv.z;
            xT[(4 * c4 + 3) * 66 + nl] = xv.w;
        }
    }
    __syncthreads();

    int wid = __builtin_amdgcn_readfirstlane(tid >> 6);   // wave id, SGPR
    const float* __restrict__ W    = (wid & 2) ? W_r : W_l;
    float* __restrict__       dstv = (wid & 2) ? xr : xl;
    int choff = (wid & 1) * 32;
    int tn = tid & 63;

    float acc[32];
    #pragma unroll
    for (int c = 0; c < 32; ++c) acc[c] = 0.f;

    #pragma unroll 2
    for (int c4 = 0; c4 < 32; ++c4) {
        float x0 = xT[(4 * c4 + 0) * 66 + tn];
        float x1 = xT[(4 * c4 + 1) * 66 + tn];
        float x2 = xT[(4 * c4 + 2) * 66 + tn];
        float x3 = xT[(4 * c4 + 3) * 66 + tn];
        #pragma unroll
        for (int cc = 0; cc < 8; ++cc) {
            const float* wrow = W + (size_t)(choff + cc * 4) * IN_CH + c4 * 4;
            float4 w0 = *(const float4*)(wrow);
            float4 w1 = *(const float4*)(wrow + IN_CH);
            float4 w2 = *(const float4*)(wrow + 2 * IN_CH);
            float4 w3 = *(const float4*)(wrow + 3 * IN_CH);
            acc[cc*4+0] = fmaf(x3, w0.w, fmaf(x2, w0.z, fmaf(x1, w0.y, fmaf(x0, w0.x, acc[cc*4+0]))));
            acc[cc*4+1] = fmaf(x3, w1.w, fmaf(x2, w1.z, fmaf(x1, w1.y, fmaf(x0, w1.x, acc[cc*4+1]))));
            acc[cc*4+2] = fmaf(x3, w2.w, fmaf(x2, w2.z, fmaf(x1, w2.y, fmaf(x0, w2.x, acc[cc*4+2]))));
            acc[cc*4+3] = fmaf(x3, w3.w, fmaf(x2, w3.z, fmaf(x1, w3.y, fmaf(x0, w3.x, acc[cc*4+3]))));
        }
    }

    int node = nb + tn;
    if (node < nN) {
        #pragma unroll
        for (int cc = 0; cc < 8; ++cc) {
            float4 o = make_float4(acc[cc*4+0], acc[cc*4+1], acc[cc*4+2], acc[cc*4+3]);
            *(float4*)(dstv + (size_t)node * HID + choff + cc * 4) = o;
        }
    }
}

// ---------------- K2: in-degree histogram (4 edges/thread) ----------------
__global__ __launch_bounds__(256) void hist_kernel(
    const int* __restrict__ dst, int* __restrict__ deg, int E)
{
    int i = (blockIdx.x * 256 + threadIdx.x) * 4;
    if (i + 3 < E) {
        int4 v = *(const int4*)(dst + i);
        atomicAdd(&deg[v.x], 1);
        atomicAdd(&deg[v.y], 1);
        atomicAdd(&deg[v.z], 1);
        atomicAdd(&deg[v.w], 1);
    } else {
        for (; i < E; ++i) atomicAdd(&deg[dst[i]], 1);
    }
}

// ---------------- K3: exclusive scan, single block, thread-contiguous ------
// np == 53248 == 1024*52. Each thread owns 52 contiguous elements in regs;
// one block scan (2 barriers) instead of 13 chunk iterations.
__global__ __launch_bounds__(1024) void scan_kernel(
    const int* __restrict__ deg, int* __restrict__ row_start,
    int* __restrict__ cursor, int np)
{
    __shared__ int wsum[16];
    int tid = threadIdx.x, lane = tid & 63, w = tid >> 6;
    int base = tid * 52;
    int4 v[13];
    #pragma unroll
    for (int i = 0; i < 13; ++i) v[i] = ((const int4*)(deg + base))[i];
    int run = 0;
    #pragma unroll
    for (int i = 0; i < 13; ++i) {
        int a;
        a = v[i].x; v[i].x = run; run += a;
        a = v[i].y; v[i].y = run; run += a;
        a = v[i].z; v[i].z = run; run += a;
        a = v[i].w; v[i].w = run; run += a;
    }
    // inclusive scan of per-thread totals across wave
    int sv = run;
    #pragma unroll
    for (int d = 1; d < 64; d <<= 1) {
        int t = __shfl_up(sv, d, 64);
        if (lane >= d) sv += t;
    }
    if (lane == 63) wsum[w] = sv;
    __syncthreads();
    if (tid < 16) {
        int t = wsum[tid];
        #pragma unroll
        for (int d = 1; d < 16; d <<= 1) {
            int u = __shfl_up(t, d, 64);
            if (tid >= d) t += u;
        }
        wsum[tid] = t;
    }
    __syncthreads();
    int off = (w ? wsum[w - 1] : 0) + (sv - run);   // thread-exclusive offset
    #pragma unroll
    for (int i = 0; i < 13; ++i) {
        int4 o = make_int4(v[i].x + off, v[i].y + off, v[i].z + off, v[i].w + off);
        ((int4*)(row_start + base))[i] = o;
        ((int4*)(cursor + base))[i] = o;
    }
}

// ---------------- K4: scatter edges into CSR slots (4 edges/thread) --------
__global__ __launch_bounds__(256) void scatter_kernel(
    const int* __restrict__ src, const int* __restrict__ dst,
    int* __restrict__ cursor, int* __restrict__ csr, int E)
{
    int i = (blockIdx.x * 256 + threadIdx.x) * 4;
    if (i + 3 < E) {
        int4 sv = *(const int4*)(src + i);
        int4 dv = *(const int4*)(dst + i);
        int p0 = atomicAdd(&cursor[dv.x], 1); csr[p0] = sv.x;
        int p1 = atomicAdd(&cursor[dv.y], 1); csr[p1] = sv.y;
        int p2 = atomicAdd(&cursor[dv.z], 1); csr[p2] = sv.z;
        int p3 = atomicAdd(&cursor[dv.w], 1); csr[p3] = sv.w;
    } else {
        for (; i < E; ++i) {
            int p = atomicAdd(&cursor[dst[i]], 1);
            csr[p] = src[i];
        }
    }
}

// ---------------- K5: fused attention + aggregation + ELU + linear ----------
// One wave per node; 4 groups x 16 lanes; lane = 4 channels. Unroll-by-8:
// two independent csr->gather->compute chains per iteration for 2x MLP.
__global__ __launch_bounds__(256) void gat_main(
    const float* __restrict__ xl, const float* __restrict__ xr,
    const int* __restrict__ row_start, const int* __restrict__ row_end,
    const int* __restrict__ csr,
    const float* __restrict__ att, const float* __restrict__ bias_conv,
    const float* __restrict__ W_lin, const float* __restrict__ b_lin,
    float* __restrict__ out, int nN)
{
    __shared__ float WT[64 * 65];   // WT[c*65+o] = W_lin[o][c], +1 pad
    __shared__ float hbuf[4][64];
    int tid = threadIdx.x;
    for (int idx = tid; idx < 64 * 64; idx += 256) {
        int o = idx >> 6, c = idx & 63;
        WT[c * 65 + o] = W_lin[idx];
    }
    int lane = tid & 63, w = tid >> 6;
    int g = lane >> 4, gl = lane & 15;
    int node = blockIdx.x * 4 + w;
    bool active = node < nN;
    if (active) {
        const float4 att4 = *(const float4*)(att + gl * 4);
        const float4 xr4  = *(const float4*)(xr + (size_t)node * HID + gl * 4);
        float4 acc = make_float4(0.f, 0.f, 0.f, 0.f);
        float denom = 0.f;
        // self loop: group 0 only
        if (g == 0) {
            float4 xs = *(const float4*)(xl + (size_t)node * HID + gl * 4);
            float tx = xs.x + xr4.x, ty = xs.y + xr4.y;
            float tz = xs.z + xr4.z, tw = xs.w + xr4.w;
            float lx = fmaxf(tx, 0.f) + NEG * fminf(tx, 0.f);
            float ly = fmaxf(ty, 0.f) + NEG * fminf(ty, 0.f);
            float lz = fmaxf(tz, 0.f) + NEG * fminf(tz, 0.f);
            float lw = fmaxf(tw, 0.f) + NEG * fminf(tw, 0.f);
            float r = att4.x * lx;
            r = fmaf(att4.y, ly, r); r = fmaf(att4.z, lz, r); r = fmaf(att4.w, lw, r);
            r += __shfl_xor(r, 1, 64);
            r += __shfl_xor(r, 2, 64);
            r += __shfl_xor(r, 4, 64);
            r += __shfl_xor(r, 8, 64);
            float ev = __expf(r);
            denom = ev;
            acc.x = ev * xs.x; acc.y = ev * xs.y;
            acc.z = ev * xs.z; acc.w = ev * xs.w;
        }
        int s = row_start[node], e = row_end[node];
        for (int base = s; base < e; base += 8) {
            int ka = base + g;
            int kb = base + 4 + g;
            int kca = ka < e ? ka : e - 1;
            int kcb = kb < e ? kb : e - 1;
            int ja = csr[kca];
            int jb = csr[kcb];
            float4 xa = *(const float4*)(xl + (size_t)ja * HID + gl * 4);
            float4 xb = *(const float4*)(xl + (size_t)jb * HID + gl * 4);
            float tax = xa.x + xr4.x, tay = xa.y + xr4.y;
            float taz = xa.z + xr4.z, taw = xa.w + xr4.w;
            float tbx = xb.x + xr4.x, tby = xb.y + xr4.y;
            float tbz = xb.z + xr4.z, tbw = xb.w + xr4.w;
            float lax = fmaxf(tax, 0.f) + NEG * fminf(tax, 0.f);
            float lay = fmaxf(tay, 0.f) + NEG * fminf(tay, 0.f);
            float laz = fmaxf(taz, 0.f) + NEG * fminf(taz, 0.f);
            float law = fmaxf(taw, 0.f) + NEG * fminf(taw, 0.f);
            float lbx = fmaxf(tbx, 0.f) + NEG * fminf(tbx, 0.f);
            float lby = fmaxf(tby, 0.f) + NEG * fminf(tby, 0.f);
            float lbz = fmaxf(tbz, 0.f) + NEG * fminf(tbz, 0.f);
            float lbw = fmaxf(tbw, 0.f) + NEG * fminf(tbw, 0.f);
            float ra = att4.x * lax;
            ra = fmaf(att4.y, lay, ra); ra = fmaf(att4.z, laz, ra); ra = fmaf(att4.w, law, ra);
            float rb = att4.x * lbx;
            rb = fmaf(att4.y, lby, rb); rb = fmaf(att4.z, lbz, rb); rb = fmaf(att4.w, lbw, rb);
            ra += __shfl_xor(ra, 1, 64);
            rb += __shfl_xor(rb, 1, 64);
            ra += __shfl_xor(ra, 2, 64);
            rb += __shfl_xor(rb, 2, 64);
            ra += __shfl_xor(ra, 4, 64);
            rb += __shfl_xor(rb, 4, 64);
            ra += __shfl_xor(ra, 8, 64);
            rb += __shfl_xor(rb, 8, 64);
            float ea = (ka < e) ? __expf(ra) : 0.f;
            float eb = (kb < e) ? __expf(rb) : 0.f;
            denom += ea + eb;
            acc.x = fmaf(ea, xa.x, acc.x); acc.x = fmaf(eb, xb.x, acc.x);
            acc.y = fmaf(ea, xa.y, acc.y); acc.y = fmaf(eb, xb.y, acc.y);
            acc.z = fmaf(ea, xa.z, acc.z); acc.z = fmaf(eb, xb.z, acc.z);
            acc.w = fmaf(ea, xa.w, acc.w); acc.w = fmaf(eb, xb.w, acc.w);
        }
        // cross-group combine
        denom += __shfl_xor(denom, 16, 64);
        denom += __shfl_xor(denom, 32, 64);
        acc.x += __shfl_xor(acc.x, 16, 64); acc.x += __shfl_xor(acc.x, 32, 64);
        acc.y += __shfl_xor(acc.y, 16, 64); acc.y += __shfl_xor(acc.y, 32, 64);
        acc.z += __shfl_xor(acc.z, 16, 64); acc.z += __shfl_xor(acc.z, 32, 64);
        acc.w += __shfl_xor(acc.w, 16, 64); acc.w += __shfl_xor(acc.w, 32, 64);
        float inv = 1.f / (denom + 1e-16f);
        float4 b4 = *(const float4*)(bias_conv + gl * 4);
        float hx = fmaf(acc.x, inv, b4.x);
        float hy = fmaf(acc.y, inv, b4.y);
        float hz = fmaf(acc.z, inv, b4.z);
        float hw = fmaf(acc.w, inv, b4.w);
        hx = (hx > 0.f) ? hx : (__expf(hx) - 1.f);
        hy = (hy > 0.f) ? hy : (__expf(hy) - 1.f);
        hz = (hz > 0.f) ? hz : (__expf(hz) - 1.f);
        hw = (hw > 0.f) ? hw : (__expf(hw) - 1.f);
        if (g == 0) {
            *(float4*)(&hbuf[w][gl * 4]) = make_float4(hx, hy, hz, hw);
        }
    }
    __syncthreads();   // covers WT staging + hbuf writes
    if (active) {
        float y = b_lin[lane];
        #pragma unroll 8
        for (int c = 0; c < 64; ++c)
            y = fmaf(WT[c * 65 + lane], hbuf[w][c], y);
        out[(size_t)node * 64 + lane] = y;
    }
}

extern "C" void kernel_launch(void* const* d_in, const int* in_sizes, int n_in,
                              void* d_out, int out_size, void* d_ws, size_t ws_size,
                              hipStream_t stream) {
    const float* x      = (const float*)d_in[0];
    const int*   ei     = (const int*)d_in[1];
    // d_in[2] = edge_weight: unused by the reference
    const float* W_l    = (const float*)d_in[3];
    const float* W_r    = (const float*)d_in[4];
    const float* att    = (const float*)d_in[5];
    const float* bias_c = (const float*)d_in[6];
    const float* W_lin  = (const float*)d_in[7];
    const float* b_lin  = (const float*)d_in[8];
    float* out = (float*)d_out;

    int N = in_sizes[0] / IN_CH;
    int E = in_sizes[2];
    const int* srcp = ei;
    const int* dstp = ei + E;

    int NP = 53248;   // 1024 * 52, >= N, int4-aligned per thread

    char* ws = (char*)d_ws;
    float* xl = (float*)ws;
    float* xr = xl + (size_t)N * HID;
    int* deg       = (int*)(xr + (size_t)N * HID);
    int* row_start = deg + NP;
    int* cursor    = row_start + NP;
    int* csr       = cursor + NP;

    hipMemsetAsync(deg, 0, (size_t)NP * sizeof(int), stream);
    proj_kernel<<<(N + 63) / 64, 256, 0, stream>>>(x, W_l, W_r, xl, xr, N);
    hist_kernel<<<(E / 4 + 255) / 256, 256, 0, stream>>>(dstp, deg, E);
    scan_kernel<<<1, 1024, 0, stream>>>(deg, row_start, cursor, NP);
    scatter_kernel<<<(E / 4 + 255) / 256, 256, 0, stream>>>(srcp, dstp, cursor, csr, E);
    gat_main<<<(N + 3) / 4, 256, 0, stream>>>(xl, xr, row_start, cursor, csr,
                                              att, bias_c, W_lin, b_lin, out, N);
}

// Round 5
// 339.622 us; speedup vs baseline: 1.2618x; 1.1284x over previous
//
#include <hip/hip_runtime.h>

#define IN_CH 128
#define HID 64
#define NEG 0.2f

// ---------------- K1: projections xl = x@W_l.T, xr = x@W_r.T + fused hist --
// 64-node tile, 512 threads (8 waves). Thread = 1 node x 16 ch.
// Wave w: matrix = w>>2, ch-quarter = (w&3)*16. W via wave-uniform s_loads.
// LDS: only x, as float4 [c4][node] stride 65 (conflict-free b128).
// Epilogue: grid-stride in-degree histogram (independent work, saves a launch).
__global__ __launch_bounds__(512, 6) void proj_kernel(
    const float* __restrict__ x, const float* __restrict__ W_l,
    const float* __restrict__ W_r,
    float* __restrict__ xl, float* __restrict__ xr,
    const int* __restrict__ dst, int* __restrict__ deg,
    int nN, int E)
{
    __shared__ float4 x4s[32 * 65];   // 33.3 KB
    int tid = threadIdx.x;
    int nb = blockIdx.x * 64;

    #pragma unroll
    for (int i = 0; i < 4; ++i) {
        int gi = i * 512 + tid;
        int nl = gi >> 5, c4 = gi & 31;
        int node = nb + nl;
        if (node < nN)
            x4s[c4 * 65 + nl] = *(const float4*)(x + (size_t)node * IN_CH + c4 * 4);
    }
    __syncthreads();

    int wid = __builtin_amdgcn_readfirstlane(tid >> 6);   // 0..7, SGPR
    const float* __restrict__ W    = (wid & 4) ? W_r : W_l;
    float* __restrict__       dstv = (wid & 4) ? xr : xl;
    int choff = (wid & 3) * 16;
    int tn = tid & 63;

    float acc[16];
    #pragma unroll
    for (int c = 0; c < 16; ++c) acc[c] = 0.f;

    #pragma unroll 2
    for (int c4 = 0; c4 < 32; ++c4) {
        float4 xv = x4s[c4 * 65 + tn];
        #pragma unroll
        for (int cc = 0; cc < 4; ++cc) {
            const float* wrow = W + (size_t)(choff + cc * 4) * IN_CH + c4 * 4;
            float4 w0 = *(const float4*)(wrow);
            float4 w1 = *(const float4*)(wrow + IN_CH);
            float4 w2 = *(const float4*)(wrow + 2 * IN_CH);
            float4 w3 = *(const float4*)(wrow + 3 * IN_CH);
            acc[cc*4+0] = fmaf(xv.w, w0.w, fmaf(xv.z, w0.z, fmaf(xv.y, w0.y, fmaf(xv.x, w0.x, acc[cc*4+0]))));
            acc[cc*4+1] = fmaf(xv.w, w1.w, fmaf(xv.z, w1.z, fmaf(xv.y, w1.y, fmaf(xv.x, w1.x, acc[cc*4+1]))));
            acc[cc*4+2] = fmaf(xv.w, w2.w, fmaf(xv.z, w2.z, fmaf(xv.y, w2.y, fmaf(xv.x, w2.x, acc[cc*4+2]))));
            acc[cc*4+3] = fmaf(xv.w, w3.w, fmaf(xv.z, w3.z, fmaf(xv.y, w3.y, fmaf(xv.x, w3.x, acc[cc*4+3]))));
        }
    }

    int node = nb + tn;
    if (node < nN) {
        #pragma unroll
        for (int cc = 0; cc < 4; ++cc) {
            float4 o = make_float4(acc[cc*4+0], acc[cc*4+1], acc[cc*4+2], acc[cc*4+3]);
            *(float4*)(dstv + (size_t)node * HID + choff + cc * 4) = o;
        }
    }

    // ---- fused in-degree histogram (grid-stride, int4) ----
    int E4 = E >> 2;
    int gstride = gridDim.x * 512;
    for (int i = blockIdx.x * 512 + tid; i < E4; i += gstride) {
        int4 v = *(const int4*)(dst + i * 4);
        atomicAdd(&deg[v.x], 1);
        atomicAdd(&deg[v.y], 1);
        atomicAdd(&deg[v.z], 1);
        atomicAdd(&deg[v.w], 1);
    }
    if (blockIdx.x == 0 && tid == 0) {
        for (int i = E4 * 4; i < E; ++i) atomicAdd(&deg[dst[i]], 1);
    }
}

// ---------------- K3: exclusive scan, single block, thread-contiguous ------
// np == 53248 == 1024*52. Each thread owns 52 contiguous elements in regs.
__global__ __launch_bounds__(1024) void scan_kernel(
    const int* __restrict__ deg, int* __restrict__ row_start,
    int* __restrict__ cursor, int np)
{
    __shared__ int wsum[16];
    int tid = threadIdx.x, lane = tid & 63, w = tid >> 6;
    int base = tid * 52;
    int4 v[13];
    #pragma unroll
    for (int i = 0; i < 13; ++i) v[i] = ((const int4*)(deg + base))[i];
    int run = 0;
    #pragma unroll
    for (int i = 0; i < 13; ++i) {
        int a;
        a = v[i].x; v[i].x = run; run += a;
        a = v[i].y; v[i].y = run; run += a;
        a = v[i].z; v[i].z = run; run += a;
        a = v[i].w; v[i].w = run; run += a;
    }
    int sv = run;
    #pragma unroll
    for (int d = 1; d < 64; d <<= 1) {
        int t = __shfl_up(sv, d, 64);
        if (lane >= d) sv += t;
    }
    if (lane == 63) wsum[w] = sv;
    __syncthreads();
    if (tid < 16) {
        int t = wsum[tid];
        #pragma unroll
        for (int d = 1; d < 16; d <<= 1) {
            int u = __shfl_up(t, d, 64);
            if (tid >= d) t += u;
        }
        wsum[tid] = t;
    }
    __syncthreads();
    int off = (w ? wsum[w - 1] : 0) + (sv - run);
    #pragma unroll
    for (int i = 0; i < 13; ++i) {
        int4 o = make_int4(v[i].x + off, v[i].y + off, v[i].z + off, v[i].w + off);
        ((int4*)(row_start + base))[i] = o;
        ((int4*)(cursor + base))[i] = o;
    }
}

// ---------------- K4: scatter edges into CSR slots (4 edges/thread) --------
__global__ __launch_bounds__(256) void scatter_kernel(
    const int* __restrict__ src, const int* __restrict__ dst,
    int* __restrict__ cursor, int* __restrict__ csr, int E)
{
    int i = (blockIdx.x * 256 + threadIdx.x) * 4;
    if (i + 3 < E) {
        int4 sv = *(const int4*)(src + i);
        int4 dv = *(const int4*)(dst + i);
        int p0 = atomicAdd(&cursor[dv.x], 1); csr[p0] = sv.x;
        int p1 = atomicAdd(&cursor[dv.y], 1); csr[p1] = sv.y;
        int p2 = atomicAdd(&cursor[dv.z], 1); csr[p2] = sv.z;
        int p3 = atomicAdd(&cursor[dv.w], 1); csr[p3] = sv.w;
    } else {
        for (; i < E; ++i) {
            int p = atomicAdd(&cursor[dst[i]], 1);
            csr[p] = src[i];
        }
    }
}

// ---------------- K5: fused attention + aggregation + ELU + linear ----------
// One wave per node; 4 groups x 16 lanes; lane = 4 channels. Unroll-by-8.
__global__ __launch_bounds__(256) void gat_main(
    const float* __restrict__ xl, const float* __restrict__ xr,
    const int* __restrict__ row_start, const int* __restrict__ row_end,
    const int* __restrict__ csr,
    const float* __restrict__ att, const float* __restrict__ bias_conv,
    const float* __restrict__ W_lin, const float* __restrict__ b_lin,
    float* __restrict__ out, int nN)
{
    __shared__ float WT[64 * 65];   // WT[c*65+o] = W_lin[o][c], +1 pad
    __shared__ float hbuf[4][64];
    int tid = threadIdx.x;
    for (int idx = tid; idx < 64 * 64; idx += 256) {
        int o = idx >> 6, c = idx & 63;
        WT[c * 65 + o] = W_lin[idx];
    }
    int lane = tid & 63, w = tid >> 6;
    int g = lane >> 4, gl = lane & 15;
    int node = blockIdx.x * 4 + w;
    bool active = node < nN;
    if (active) {
        const float4 att4 = *(const float4*)(att + gl * 4);
        const float4 xr4  = *(const float4*)(xr + (size_t)node * HID + gl * 4);
        float4 acc = make_float4(0.f, 0.f, 0.f, 0.f);
        float denom = 0.f;
        if (g == 0) {
            float4 xs = *(const float4*)(xl + (size_t)node * HID + gl * 4);
            float tx = xs.x + xr4.x, ty = xs.y + xr4.y;
            float tz = xs.z + xr4.z, tw = xs.w + xr4.w;
            float lx = fmaxf(tx, 0.f) + NEG * fminf(tx, 0.f);
            float ly = fmaxf(ty, 0.f) + NEG * fminf(ty, 0.f);
            float lz = fmaxf(tz, 0.f) + NEG * fminf(tz, 0.f);
            float lw = fmaxf(tw, 0.f) + NEG * fminf(tw, 0.f);
            float r = att4.x * lx;
            r = fmaf(att4.y, ly, r); r = fmaf(att4.z, lz, r); r = fmaf(att4.w, lw, r);
            r += __shfl_xor(r, 1, 64);
            r += __shfl_xor(r, 2, 64);
            r += __shfl_xor(r, 4, 64);
            r += __shfl_xor(r, 8, 64);
            float ev = __expf(r);
            denom = ev;
            acc.x = ev * xs.x; acc.y = ev * xs.y;
            acc.z = ev * xs.z; acc.w = ev * xs.w;
        }
        int s = row_start[node], e = row_end[node];
        for (int base = s; base < e; base += 8) {
            int ka = base + g;
            int kb = base + 4 + g;
            int kca = ka < e ? ka : e - 1;
            int kcb = kb < e ? kb : e - 1;
            int ja = csr[kca];
            int jb = csr[kcb];
            float4 xa = *(const float4*)(xl + (size_t)ja * HID + gl * 4);
            float4 xb = *(const float4*)(xl + (size_t)jb * HID + gl * 4);
            float tax = xa.x + xr4.x, tay = xa.y + xr4.y;
            float taz = xa.z + xr4.z, taw = xa.w + xr4.w;
            float tbx = xb.x + xr4.x, tby = xb.y + xr4.y;
            float tbz = xb.z + xr4.z, tbw = xb.w + xr4.w;
            float lax = fmaxf(tax, 0.f) + NEG * fminf(tax, 0.f);
            float lay = fmaxf(tay, 0.f) + NEG * fminf(tay, 0.f);
            float laz = fmaxf(taz, 0.f) + NEG * fminf(taz, 0.f);
            float law = fmaxf(taw, 0.f) + NEG * fminf(taw, 0.f);
            float lbx = fmaxf(tbx, 0.f) + NEG * fminf(tbx, 0.f);
            float lby = fmaxf(tby, 0.f) + NEG * fminf(tby, 0.f);
            float lbz = fmaxf(tbz, 0.f) + NEG * fminf(tbz, 0.f);
            float lbw = fmaxf(tbw, 0.f) + NEG * fminf(tbw, 0.f);
            float ra = att4.x * lax;
            ra = fmaf(att4.y, lay, ra); ra = fmaf(att4.z, laz, ra); ra = fmaf(att4.w, law, ra);
            float rb = att4.x * lbx;
            rb = fmaf(att4.y, lby, rb); rb = fmaf(att4.z, lbz, rb); rb = fmaf(att4.w, lbw, rb);
            ra += __shfl_xor(ra, 1, 64);
            rb += __shfl_xor(rb, 1, 64);
            ra += __shfl_xor(ra, 2, 64);
            rb += __shfl_xor(rb, 2, 64);
            ra += __shfl_xor(ra, 4, 64);
            rb += __shfl_xor(rb, 4, 64);
            ra += __shfl_xor(ra, 8, 64);
            rb += __shfl_xor(rb, 8, 64);
            float ea = (ka < e) ? __expf(ra) : 0.f;
            float eb = (kb < e) ? __expf(rb) : 0.f;
            denom += ea + eb;
            acc.x = fmaf(ea, xa.x, acc.x); acc.x = fmaf(eb, xb.x, acc.x);
            acc.y = fmaf(ea, xa.y, acc.y); acc.y = fmaf(eb, xb.y, acc.y);
            acc.z = fmaf(ea, xa.z, acc.z); acc.z = fmaf(eb, xb.z, acc.z);
            acc.w = fmaf(ea, xa.w, acc.w); acc.w = fmaf(eb, xb.w, acc.w);
        }
        denom += __shfl_xor(denom, 16, 64);
        denom += __shfl_xor(denom, 32, 64);
        acc.x += __shfl_xor(acc.x, 16, 64); acc.x += __shfl_xor(acc.x, 32, 64);
        acc.y += __shfl_xor(acc.y, 16, 64); acc.y += __shfl_xor(acc.y, 32, 64);
        acc.z += __shfl_xor(acc.z, 16, 64); acc.z += __shfl_xor(acc.z, 32, 64);
        acc.w += __shfl_xor(acc.w, 16, 64); acc.w += __shfl_xor(acc.w, 32, 64);
        float inv = 1.f / (denom + 1e-16f);
        float4 b4 = *(const float4*)(bias_conv + gl * 4);
        float hx = fmaf(acc.x, inv, b4.x);
        float hy = fmaf(acc.y, inv, b4.y);
        float hz = fmaf(acc.z, inv, b4.z);
        float hw = fmaf(acc.w, inv, b4.w);
        hx = (hx > 0.f) ? hx : (__expf(hx) - 1.f);
        hy = (hy > 0.f) ? hy : (__expf(hy) - 1.f);
        hz = (hz > 0.f) ? hz : (__expf(hz) - 1.f);
        hw = (hw > 0.f) ? hw : (__expf(hw) - 1.f);
        if (g == 0) {
            *(float4*)(&hbuf[w][gl * 4]) = make_float4(hx, hy, hz, hw);
        }
    }
    __syncthreads();
    if (active) {
        float y = b_lin[lane];
        #pragma unroll 8
        for (int c = 0; c < 64; ++c)
            y = fmaf(WT[c * 65 + lane], hbuf[w][c], y);
        out[(size_t)node * 64 + lane] = y;
    }
}

extern "C" void kernel_launch(void* const* d_in, const int* in_sizes, int n_in,
                              void* d_out, int out_size, void* d_ws, size_t ws_size,
                              hipStream_t stream) {
    const float* x      = (const float*)d_in[0];
    const int*   ei     = (const int*)d_in[1];
    // d_in[2] = edge_weight: unused by the reference
    const float* W_l    = (const float*)d_in[3];
    const float* W_r    = (const float*)d_in[4];
    const float* att    = (const float*)d_in[5];
    const float* bias_c = (const float*)d_in[6];
    const float* W_lin  = (const float*)d_in[7];
    const float* b_lin  = (const float*)d_in[8];
    float* out = (float*)d_out;

    int N = in_sizes[0] / IN_CH;
    int E = in_sizes[2];
    const int* srcp = ei;
    const int* dstp = ei + E;

    int NP = 53248;   // 1024 * 52, >= N, int4-aligned per thread

    char* ws = (char*)d_ws;
    float* xl = (float*)ws;
    float* xr = xl + (size_t)N * HID;
    int* deg       = (int*)(xr + (size_t)N * HID);
    int* row_start = deg + NP;
    int* cursor    = row_start + NP;
    int* csr       = cursor + NP;

    hipMemsetAsync(deg, 0, (size_t)NP * sizeof(int), stream);
    proj_kernel<<<(N + 63) / 64, 512, 0, stream>>>(x, W_l, W_r, xl, xr,
                                                   dstp, deg, N, E);
    scan_kernel<<<1, 1024, 0, stream>>>(deg, row_start, cursor, NP);
    scatter_kernel<<<(E / 4 + 255) / 256, 256, 0, stream>>>(srcp, dstp, cursor, csr, E);
    gat_main<<<(N + 3) / 4, 256, 0, stream>>>(xl, xr, row_start, cursor, csr,
                                              att, bias_c, W_lin, b_lin, out, N);
}